// Round 3
// baseline (2977.546 us; speedup 1.0000x reference)
//
#include <hip/hip_runtime.h>
#include <hip/hip_bf16.h>
#include <stdint.h>

typedef __attribute__((ext_vector_type(8))) short short8;
typedef __attribute__((ext_vector_type(4))) short short4v;
typedef __attribute__((ext_vector_type(4))) float f32x4;
typedef __attribute__((ext_vector_type(4))) int int4v;

#define T_STEPS 512
#define BATCH 64
#define HDIM 1024
#define MROWS (T_STEPS * BATCH)  // 32768

__device__ __forceinline__ unsigned short f2bf(float f) {
  unsigned int u = __float_as_uint(f);
  u += 0x7FFFu + ((u >> 16) & 1u);  // RNE
  return (unsigned short)(u >> 16);
}

// ---------------- transpose + convert: dst[n][k] = bf16(src[k][n]), 1024x1024
__global__ __launch_bounds__(256) void transpose_cvt(const float* __restrict__ src,
                                                     unsigned short* __restrict__ dst) {
  __shared__ unsigned short tile[32][36];
  int b = blockIdx.x;
  int tr = b >> 5, tc = b & 31;
  int t = threadIdx.x;
  int i = t >> 3, j4 = (t & 7) << 2;
  const float4 v = *(const float4*)(src + (size_t)(tr * 32 + i) * 1024 + tc * 32 + j4);
  tile[i][j4 + 0] = f2bf(v.x);
  tile[i][j4 + 1] = f2bf(v.y);
  tile[i][j4 + 2] = f2bf(v.z);
  tile[i][j4 + 3] = f2bf(v.w);
  __syncthreads();
  int c = t >> 3, r4 = (t & 7) << 2;
  short4v o;
  o[0] = (short)tile[r4 + 0][c];
  o[1] = (short)tile[r4 + 1][c];
  o[2] = (short)tile[r4 + 2][c];
  o[3] = (short)tile[r4 + 3][c];
  *(short4v*)(dst + (size_t)(tc * 32 + c) * 1024 + tr * 32 + r4) = o;
}

// ---------------- xW GEMM: C[M,1024] = A[M,1024] @ B + bias, B given as B^T bf16 [N][K]
__global__ __launch_bounds__(256, 2) void xw_gemm(const float* __restrict__ A,
                                                  const unsigned short* __restrict__ BT,
                                                  const float* __restrict__ bias,
                                                  float* __restrict__ C) {
  __shared__ unsigned short As[128][40];
  __shared__ unsigned short Bs[128][40];
  int b = blockIdx.x;
  int swz = (b & 7) * 256 + (b >> 3);
  int tn = swz & 7, tm = swz >> 3;
  int t = threadIdx.x, lane = t & 63, wave = t >> 6;
  int l15 = lane & 15, l4 = lane >> 4;
  int wm = wave >> 1, wn = wave & 1;

  f32x4 acc[4][4];
#pragma unroll
  for (int i = 0; i < 4; ++i)
#pragma unroll
    for (int j = 0; j < 4; ++j) acc[i][j] = (f32x4){0.f, 0.f, 0.f, 0.f};

  int sm = t >> 1, sh = (t & 1) << 4;
  const float* a_src = A + (size_t)(tm * 128 + sm) * 1024 + sh;
  const unsigned short* b_src = BT + (size_t)(tn * 128 + sm) * 1024 + sh;

  for (int kt = 0; kt < 32; ++kt) {
    float4 av0 = *(const float4*)(a_src + kt * 32 + 0);
    float4 av1 = *(const float4*)(a_src + kt * 32 + 4);
    float4 av2 = *(const float4*)(a_src + kt * 32 + 8);
    float4 av3 = *(const float4*)(a_src + kt * 32 + 12);
    short8 w0, w1;
    w0[0] = (short)f2bf(av0.x); w0[1] = (short)f2bf(av0.y);
    w0[2] = (short)f2bf(av0.z); w0[3] = (short)f2bf(av0.w);
    w0[4] = (short)f2bf(av1.x); w0[5] = (short)f2bf(av1.y);
    w0[6] = (short)f2bf(av1.z); w0[7] = (short)f2bf(av1.w);
    w1[0] = (short)f2bf(av2.x); w1[1] = (short)f2bf(av2.y);
    w1[2] = (short)f2bf(av2.z); w1[3] = (short)f2bf(av2.w);
    w1[4] = (short)f2bf(av3.x); w1[5] = (short)f2bf(av3.y);
    w1[6] = (short)f2bf(av3.z); w1[7] = (short)f2bf(av3.w);
    *(short8*)&As[sm][sh] = w0;
    *(short8*)&As[sm][sh + 8] = w1;
    short8 bv0 = *(const short8*)(b_src + kt * 32 + 0);
    short8 bv1 = *(const short8*)(b_src + kt * 32 + 8);
    *(short8*)&Bs[sm][sh] = bv0;
    *(short8*)&Bs[sm][sh + 8] = bv1;
    __syncthreads();

    short8 af[4], bfr[4];
#pragma unroll
    for (int i = 0; i < 4; ++i) af[i] = *(const short8*)&As[wm * 64 + i * 16 + l15][8 * l4];
#pragma unroll
    for (int j = 0; j < 4; ++j) bfr[j] = *(const short8*)&Bs[wn * 64 + j * 16 + l15][8 * l4];
#pragma unroll
    for (int i = 0; i < 4; ++i)
#pragma unroll
      for (int j = 0; j < 4; ++j)
        acc[i][j] = __builtin_amdgcn_mfma_f32_16x16x32_bf16(af[i], bfr[j], acc[i][j], 0, 0, 0);
    __syncthreads();
  }

#pragma unroll
  for (int i = 0; i < 4; ++i) {
    int row0 = tm * 128 + wm * 64 + i * 16 + l4 * 4;
#pragma unroll
    for (int j = 0; j < 4; ++j) {
      int col = tn * 128 + wn * 64 + j * 16 + l15;
      float bv = bias[col];
#pragma unroll
      for (int r = 0; r < 4; ++r)
        C[(size_t)(row0 + r) * 1024 + col] = acc[i][j][r] + bv;
    }
  }
}

// ---------------- coherent access helpers (sc0 sc1 = device coherence point,
// bypassing the non-coherent per-XCD L1/L2; no cache-maintenance ops anywhere)
__device__ __forceinline__ void coh_store_dword(int* p, int v) {
  asm volatile("global_store_dword %0, %1, off sc0 sc1" ::"v"(p), "v"(v) : "memory");
}
__device__ __forceinline__ void coh_load_dwordx4_issue(int4v* dst, const int* p) {
  asm volatile("global_load_dwordx4 %0, %1, off sc0 sc1" : "=&v"(*dst) : "v"(p) : "memory");
}

// ---------------- persistent recurrent scan, tagged-data protocol
// h element = dword: (step+1)<<16 | bf16(h).  Consumers poll the data itself;
// tag match => payload already in registers. No flags, no drains, no fences.
// 256 WGs x 4 waves; WG=(bg,cg) owns 16x16 output tile; wave w covers K slice
// [256w,256w+256) -> 8 MFMAs; LDS reduce across waves; per-thread epilogue.
// Slot reuse (step s+2 overwrites slot s&1) is safe: writing h_{s+2} requires
// having observed ALL of h_{s+1}, which implies every WG of this bg finished
// reading h_s (its loads completed before its h_{s+1} stores were visible).
__global__ __launch_bounds__(256, 1) void rnn_scan(const unsigned short* __restrict__ whhT,
                                                   float* __restrict__ out,
                                                   int* __restrict__ hbuf) {
  int wg = blockIdx.x;
  int xcd = wg & 7;
  int bg = xcd >> 1;                        // 0..3
  int cg = ((wg >> 3) << 1) | (xcd & 1);    // 0..63
  int t = threadIdx.x, lane = t & 63, wave = t >> 6;
  int l15 = lane & 15, l4 = lane >> 4;

  __shared__ __align__(16) float red[4][64][4];

  // W_hh^T B-fragments for this wave's K-slice: registers for all 512 steps.
  short8 bfrag[8];
#pragma unroll
  for (int i = 0; i < 8; ++i)
    bfrag[i] = *(const short8*)(whhT + (size_t)(cg * 16 + l15) * 1024 + wave * 256 + i * 32 + 8 * l4);

  int row = bg * 16 + l4 * 4 + wave;  // batch index this thread outputs
  int col = cg * 16 + l15;            // hidden index this thread outputs
  const int* cons_base0 = hbuf + (size_t)(bg * 16 + l15) * 1024 + wave * 256 + 8 * l4;
  int* prod_base = hbuf + (size_t)row * 1024 + col;

  for (int s = 0; s < T_STEPS; ++s) {
    // prefetch this step's xW value BEFORE the poll (latency hides under wait)
    size_t oidx = ((size_t)s * BATCH + row) * HDIM + col;
    float xw = out[oidx];

    f32x4 acc = (f32x4){0.f, 0.f, 0.f, 0.f};
    if (s > 0) {
      const int* cb = cons_base0 + (size_t)((s - 1) & 1) * BATCH * HDIM;
      unsigned int tagv = (unsigned int)s;  // tag of h_{s-1} is (s-1)+1
      int4v q[16];
      for (;;) {
#pragma unroll
        for (int i = 0; i < 8; ++i) {
          coh_load_dwordx4_issue(&q[2 * i], cb + i * 32);
          coh_load_dwordx4_issue(&q[2 * i + 1], cb + i * 32 + 4);
        }
        asm volatile("s_waitcnt vmcnt(0)" ::: "memory");
        __builtin_amdgcn_sched_barrier(0);
        unsigned int bad = 0;
#pragma unroll
        for (int i = 0; i < 16; ++i) {
          bad |= ((unsigned int)q[i][0] >> 16) ^ tagv;
          bad |= ((unsigned int)q[i][1] >> 16) ^ tagv;
          bad |= ((unsigned int)q[i][2] >> 16) ^ tagv;
          bad |= ((unsigned int)q[i][3] >> 16) ^ tagv;
        }
        if (__all(bad == 0)) break;
        __builtin_amdgcn_s_sleep(1);
      }
      // pack payload lo16s -> bf16 A-fragments, 8 MFMAs over K=256
#pragma unroll
      for (int i = 0; i < 8; ++i) {
        int4v lo = q[2 * i], hi = q[2 * i + 1];
        int4v pk;
        pk[0] = (lo[0] & 0xffff) | (lo[1] << 16);
        pk[1] = (lo[2] & 0xffff) | (lo[3] << 16);
        pk[2] = (hi[0] & 0xffff) | (hi[1] << 16);
        pk[3] = (hi[2] & 0xffff) | (hi[3] << 16);
        acc = __builtin_amdgcn_mfma_f32_16x16x32_bf16(*(short8*)&pk, bfrag[i], acc, 0, 0, 0);
      }
    }
    *(f32x4*)&red[wave][lane][0] = acc;
    __syncthreads();
    float sum = red[0][lane][wave] + red[1][lane][wave] + red[2][lane][wave] + red[3][lane][wave];
    float hv = tanhf(xw + sum);
    out[oidx] = hv;  // normal cached store (private to this thread)
    // tagged coherent h publish — no drain, no flag: the data IS the flag
    coh_store_dword(prod_base + (size_t)(s & 1) * BATCH * HDIM,
                    (int)(((unsigned int)(s + 1) << 16) | (unsigned int)f2bf(hv)));
    if (s == T_STEPS - 1)
      out[(size_t)MROWS * HDIM + (size_t)row * HDIM + col] = hv;  // last_state
    __syncthreads();  // protect red[] against next-iteration overwrite
  }
}

extern "C" void kernel_launch(void* const* d_in, const int* in_sizes, int n_in,
                              void* d_out, int out_size, void* d_ws, size_t ws_size,
                              hipStream_t stream) {
  const float* inp = (const float*)d_in[0];   // [512,64,1024] fp32
  const float* wxh = (const float*)d_in[1];   // [1024,1024]
  const float* whh = (const float*)d_in[2];   // [1024,1024]
  const float* bh  = (const float*)d_in[3];   // [1024]
  float* out = (float*)d_out;

  char* ws = (char*)d_ws;
  unsigned short* whhT = (unsigned short*)(ws);                 // 2 MB
  unsigned short* wxhT = (unsigned short*)(ws + (2u << 20));    // 2 MB
  int* hbuf = (int*)(ws + (4u << 20));                          // 512 KB tagged ping-pong

  // clear stale tags from previous replays (tags start at 1; 0 never matches)
  hipMemsetAsync(hbuf, 0, 2u * BATCH * HDIM * sizeof(int), stream);
  transpose_cvt<<<1024, 256, 0, stream>>>(whh, whhT);
  transpose_cvt<<<1024, 256, 0, stream>>>(wxh, wxhT);
  xw_gemm<<<2048, 256, 0, stream>>>(inp, wxhT, bh, out);
  rnn_scan<<<256, 256, 0, stream>>>(whhT, out, hbuf);
}

// Round 4
// 2666.688 us; speedup vs baseline: 1.1166x; 1.1166x over previous
//
#include <hip/hip_runtime.h>
#include <hip/hip_bf16.h>
#include <stdint.h>

typedef __attribute__((ext_vector_type(8))) short short8;
typedef __attribute__((ext_vector_type(4))) short short4v;
typedef __attribute__((ext_vector_type(4))) float f32x4;
typedef __attribute__((ext_vector_type(4))) int int4v;

#define T_STEPS 512
#define BATCH 64
#define HDIM 1024
#define MROWS (T_STEPS * BATCH)  // 32768

__device__ __forceinline__ unsigned short f2bf(float f) {
  unsigned int u = __float_as_uint(f);
  u += 0x7FFFu + ((u >> 16) & 1u);  // RNE
  return (unsigned short)(u >> 16);
}

// ---------------- transpose + convert: dst[n][k] = bf16(src[k][n]), 1024x1024
__global__ __launch_bounds__(256) void transpose_cvt(const float* __restrict__ src,
                                                     unsigned short* __restrict__ dst) {
  __shared__ unsigned short tile[32][36];
  int b = blockIdx.x;
  int tr = b >> 5, tc = b & 31;
  int t = threadIdx.x;
  int i = t >> 3, j4 = (t & 7) << 2;
  const float4 v = *(const float4*)(src + (size_t)(tr * 32 + i) * 1024 + tc * 32 + j4);
  tile[i][j4 + 0] = f2bf(v.x);
  tile[i][j4 + 1] = f2bf(v.y);
  tile[i][j4 + 2] = f2bf(v.z);
  tile[i][j4 + 3] = f2bf(v.w);
  __syncthreads();
  int c = t >> 3, r4 = (t & 7) << 2;
  short4v o;
  o[0] = (short)tile[r4 + 0][c];
  o[1] = (short)tile[r4 + 1][c];
  o[2] = (short)tile[r4 + 2][c];
  o[3] = (short)tile[r4 + 3][c];
  *(short4v*)(dst + (size_t)(tc * 32 + c) * 1024 + tr * 32 + r4) = o;
}

// ---------------- xW GEMM: C[M,1024] = A[M,1024] @ B + bias, B given as B^T bf16 [N][K]
__global__ __launch_bounds__(256, 2) void xw_gemm(const float* __restrict__ A,
                                                  const unsigned short* __restrict__ BT,
                                                  const float* __restrict__ bias,
                                                  float* __restrict__ C) {
  __shared__ unsigned short As[128][40];
  __shared__ unsigned short Bs[128][40];
  int b = blockIdx.x;
  int swz = (b & 7) * 256 + (b >> 3);
  int tn = swz & 7, tm = swz >> 3;
  int t = threadIdx.x, lane = t & 63, wave = t >> 6;
  int l15 = lane & 15, l4 = lane >> 4;
  int wm = wave >> 1, wn = wave & 1;

  f32x4 acc[4][4];
#pragma unroll
  for (int i = 0; i < 4; ++i)
#pragma unroll
    for (int j = 0; j < 4; ++j) acc[i][j] = (f32x4){0.f, 0.f, 0.f, 0.f};

  int sm = t >> 1, sh = (t & 1) << 4;
  const float* a_src = A + (size_t)(tm * 128 + sm) * 1024 + sh;
  const unsigned short* b_src = BT + (size_t)(tn * 128 + sm) * 1024 + sh;

  for (int kt = 0; kt < 32; ++kt) {
    float4 av0 = *(const float4*)(a_src + kt * 32 + 0);
    float4 av1 = *(const float4*)(a_src + kt * 32 + 4);
    float4 av2 = *(const float4*)(a_src + kt * 32 + 8);
    float4 av3 = *(const float4*)(a_src + kt * 32 + 12);
    short8 w0, w1;
    w0[0] = (short)f2bf(av0.x); w0[1] = (short)f2bf(av0.y);
    w0[2] = (short)f2bf(av0.z); w0[3] = (short)f2bf(av0.w);
    w0[4] = (short)f2bf(av1.x); w0[5] = (short)f2bf(av1.y);
    w0[6] = (short)f2bf(av1.z); w0[7] = (short)f2bf(av1.w);
    w1[0] = (short)f2bf(av2.x); w1[1] = (short)f2bf(av2.y);
    w1[2] = (short)f2bf(av2.z); w1[3] = (short)f2bf(av2.w);
    w1[4] = (short)f2bf(av3.x); w1[5] = (short)f2bf(av3.y);
    w1[6] = (short)f2bf(av3.z); w1[7] = (short)f2bf(av3.w);
    *(short8*)&As[sm][sh] = w0;
    *(short8*)&As[sm][sh + 8] = w1;
    short8 bv0 = *(const short8*)(b_src + kt * 32 + 0);
    short8 bv1 = *(const short8*)(b_src + kt * 32 + 8);
    *(short8*)&Bs[sm][sh] = bv0;
    *(short8*)&Bs[sm][sh + 8] = bv1;
    __syncthreads();

    short8 af[4], bfr[4];
#pragma unroll
    for (int i = 0; i < 4; ++i) af[i] = *(const short8*)&As[wm * 64 + i * 16 + l15][8 * l4];
#pragma unroll
    for (int j = 0; j < 4; ++j) bfr[j] = *(const short8*)&Bs[wn * 64 + j * 16 + l15][8 * l4];
#pragma unroll
    for (int i = 0; i < 4; ++i)
#pragma unroll
      for (int j = 0; j < 4; ++j)
        acc[i][j] = __builtin_amdgcn_mfma_f32_16x16x32_bf16(af[i], bfr[j], acc[i][j], 0, 0, 0);
    __syncthreads();
  }

#pragma unroll
  for (int i = 0; i < 4; ++i) {
    int row0 = tm * 128 + wm * 64 + i * 16 + l4 * 4;
#pragma unroll
    for (int j = 0; j < 4; ++j) {
      int col = tn * 128 + wn * 64 + j * 16 + l15;
      float bv = bias[col];
#pragma unroll
      for (int r = 0; r < 4; ++r)
        C[(size_t)(row0 + r) * 1024 + col] = acc[i][j][r] + bv;
    }
  }
}

// ---------------- coherent access helpers (sc0 sc1 = device coherence point)
__device__ __forceinline__ void coh_store_dword(int* p, int v) {
  asm volatile("global_store_dword %0, %1, off sc0 sc1" ::"v"(p), "v"(v) : "memory");
}
__device__ __forceinline__ void coh_load_dwordx4_issue(int4v* dst, const int* p) {
  asm volatile("global_load_dwordx4 %0, %1, off sc0 sc1" : "=&v"(*dst) : "v"(p) : "memory");
}

// ---------------- persistent recurrent scan, tagged-data + cheap-sentinel detection
// 64 WGs x 4 waves. WG (bg=wg>>4, cg=wg&15) owns output tile rows [16bg,+16) x
// cols [64cg,+64). Wave w: K-slice [256w,+256), W_hh^T frags resident in 128
// VGPRs/lane; 4 colblk f32x4 accs; double-buffered LDS reduce, ONE barrier/step.
// h element = dword (step+1)<<16 | bf16(h), 2-slot ping-pong.
// Detection: poll 16B/lane sentinel (spread over rowsxchunksxproducer-waves);
// then bulk-load 64 dwords/lane ONCE and verify every tag (retry rare).
// Slot-reuse safety: the per-step barrier joins 4 waves whose loads collectively
// observed ALL 16 peer chunks; epilogue stores follow the barrier, so a WG
// writing tag s+3 proves every peer finished reading tag s+1 (transitive
// happens-before through the coherence point).
__global__ __launch_bounds__(256, 1) void rnn_scan(const unsigned short* __restrict__ whhT,
                                                   float* __restrict__ out,
                                                   int* __restrict__ hbuf) {
  int wg = blockIdx.x;
  int bg = wg >> 4;   // 0..3   (16 batch rows)
  int cg = wg & 15;   // 0..15  (64 hidden cols)
  int t = threadIdx.x, lane = t & 63, wave = t >> 6;
  int l15 = lane & 15, l4 = lane >> 4;

  __shared__ __align__(16) float red[2][4][64][4][4];  // [buf][wave][lane][colblk][4]

  // W_hh^T fragments: cols [64cg+16c+l15], K = 256*wave + 32m + 8*l4 .. +8
  short8 wfrag[4][8];
#pragma unroll
  for (int c = 0; c < 4; ++c)
#pragma unroll
    for (int m = 0; m < 8; ++m)
      wfrag[c][m] = *(const short8*)(whhT + (size_t)(64 * cg + 16 * c + l15) * 1024 +
                                     256 * wave + 32 * m + 8 * l4);

  int colw = 64 * cg + 16 * wave + l15;  // epilogue column (colblk = own wave)

  for (int s = 0; s < T_STEPS; ++s) {
    // prefetch this step's 4 xW values before the wait
    float xw[4];
#pragma unroll
    for (int r = 0; r < 4; ++r)
      xw[r] = out[((size_t)s * BATCH + bg * 16 + l4 * 4 + r) * HDIM + colw];

    f32x4 acc[4];
#pragma unroll
    for (int c = 0; c < 4; ++c) acc[c] = (f32x4){0.f, 0.f, 0.f, 0.f};

    if (s > 0) {
      const unsigned tagv = (unsigned)s;  // tag of h_{s-1}
      const int* base = hbuf + (((s - 1) & 1) << 16) + (16 * bg + l15) * 1024 + 256 * wave;
      const int* sp = base + 64 * l4 + 4 * l15;  // sentinel: rows x chunks x prod-waves
      int4v q[16];
      for (;;) {
        // cheap sentinel poll (first probe immediate)
        for (;;) {
          int4v sv;
          coh_load_dwordx4_issue(&sv, sp);
          asm volatile("s_waitcnt vmcnt(0)" ::: "memory");
          unsigned bad = (((unsigned)sv[0] >> 16) ^ tagv) | (((unsigned)sv[1] >> 16) ^ tagv) |
                         (((unsigned)sv[2] >> 16) ^ tagv) | (((unsigned)sv[3] >> 16) ^ tagv);
          if (__all(bad == 0)) break;
          __builtin_amdgcn_s_sleep(2);
        }
        // bulk load: 4 chunks x 16 dwords (K = 64jj + 8l4 .. +8 and +32)
#pragma unroll
        for (int jj = 0; jj < 4; ++jj) {
          const int* fb = base + 64 * jj + 8 * l4;
          coh_load_dwordx4_issue(&q[jj * 4 + 0], fb);
          coh_load_dwordx4_issue(&q[jj * 4 + 1], fb + 4);
          coh_load_dwordx4_issue(&q[jj * 4 + 2], fb + 32);
          coh_load_dwordx4_issue(&q[jj * 4 + 3], fb + 36);
        }
        asm volatile("s_waitcnt vmcnt(0)" ::: "memory");
        __builtin_amdgcn_sched_barrier(0);
        unsigned bad = 0;
#pragma unroll
        for (int i = 0; i < 16; ++i) {
          bad |= (((unsigned)q[i][0] >> 16) ^ tagv) | (((unsigned)q[i][1] >> 16) ^ tagv) |
                 (((unsigned)q[i][2] >> 16) ^ tagv) | (((unsigned)q[i][3] >> 16) ^ tagv);
        }
        if (__all(bad == 0)) break;
        __builtin_amdgcn_s_sleep(1);
      }
      // pack payload lo16s -> bf16 A-frags; 8 MFMAs x 4 colblks
#pragma unroll
      for (int jj = 0; jj < 4; ++jj) {
        int4v a0 = q[jj * 4 + 0], a1 = q[jj * 4 + 1], a2 = q[jj * 4 + 2], a3 = q[jj * 4 + 3];
        int4v p0, p1;
        p0[0] = (a0[0] & 0xffff) | (a0[1] << 16);
        p0[1] = (a0[2] & 0xffff) | (a0[3] << 16);
        p0[2] = (a1[0] & 0xffff) | (a1[1] << 16);
        p0[3] = (a1[2] & 0xffff) | (a1[3] << 16);
        p1[0] = (a2[0] & 0xffff) | (a2[1] << 16);
        p1[1] = (a2[2] & 0xffff) | (a2[3] << 16);
        p1[2] = (a3[0] & 0xffff) | (a3[1] << 16);
        p1[3] = (a3[2] & 0xffff) | (a3[3] << 16);
#pragma unroll
        for (int c = 0; c < 4; ++c) {
          acc[c] = __builtin_amdgcn_mfma_f32_16x16x32_bf16(*(short8*)&p0, wfrag[c][2 * jj],
                                                           acc[c], 0, 0, 0);
          acc[c] = __builtin_amdgcn_mfma_f32_16x16x32_bf16(*(short8*)&p1, wfrag[c][2 * jj + 1],
                                                           acc[c], 0, 0, 0);
        }
      }
    }

    int p = s & 1;
#pragma unroll
    for (int c = 0; c < 4; ++c) *(f32x4*)&red[p][wave][lane][c][0] = acc[c];
    __syncthreads();  // the single per-step barrier (joins all peers' observations)
    f32x4 hsum;
#pragma unroll
    for (int r = 0; r < 4; ++r)
      hsum[r] = red[p][0][lane][wave][r] + red[p][1][lane][wave][r] +
                red[p][2][lane][wave][r] + red[p][3][lane][wave][r];

#pragma unroll
    for (int r = 0; r < 4; ++r) {
      int row = bg * 16 + l4 * 4 + r;
      size_t oidx = ((size_t)s * BATCH + row) * HDIM + colw;
      float hv = tanhf(xw[r] + hsum[r]);
      out[oidx] = hv;  // normal cached store (private to this thread)
      if (s != T_STEPS - 1)
        coh_store_dword(hbuf + ((s & 1) << 16) + row * 1024 + colw,
                        (int)(((unsigned)(s + 1) << 16) | (unsigned)f2bf(hv)));
      else
        out[(size_t)MROWS * HDIM + (size_t)row * HDIM + colw] = hv;  // last_state
    }
  }
}

extern "C" void kernel_launch(void* const* d_in, const int* in_sizes, int n_in,
                              void* d_out, int out_size, void* d_ws, size_t ws_size,
                              hipStream_t stream) {
  const float* inp = (const float*)d_in[0];   // [512,64,1024] fp32
  const float* wxh = (const float*)d_in[1];   // [1024,1024]
  const float* whh = (const float*)d_in[2];   // [1024,1024]
  const float* bh  = (const float*)d_in[3];   // [1024]
  float* out = (float*)d_out;

  char* ws = (char*)d_ws;
  unsigned short* whhT = (unsigned short*)(ws);                 // 2 MB
  unsigned short* wxhT = (unsigned short*)(ws + (2u << 20));    // 2 MB
  int* hbuf = (int*)(ws + (4u << 20));                          // 512 KB tagged ping-pong

  // clear stale tags from previous replays (tag 0 never matches; 0xAA poison safe too)
  hipMemsetAsync(hbuf, 0, 2u * BATCH * HDIM * sizeof(int), stream);
  transpose_cvt<<<1024, 256, 0, stream>>>(whh, whhT);
  transpose_cvt<<<1024, 256, 0, stream>>>(wxh, wxhT);
  xw_gemm<<<2048, 256, 0, stream>>>(inp, wxhT, bh, out);
  rnn_scan<<<64, 256, 0, stream>>>(whhT, out, hbuf);
}

// Round 8
// 2623.235 us; speedup vs baseline: 1.1351x; 1.0166x over previous
//
#include <hip/hip_runtime.h>
#include <hip/hip_bf16.h>
#include <stdint.h>

typedef __attribute__((ext_vector_type(8))) short short8;
typedef __attribute__((ext_vector_type(4))) short short4v;
typedef __attribute__((ext_vector_type(4))) float f32x4;
typedef __attribute__((ext_vector_type(4))) int int4v;

#define T_STEPS 512
#define BATCH 64
#define HDIM 1024
#define MROWS (T_STEPS * BATCH)  // 32768

__device__ __forceinline__ unsigned short f2bf(float f) {
  unsigned int u = __float_as_uint(f);
  u += 0x7FFFu + ((u >> 16) & 1u);  // RNE
  return (unsigned short)(u >> 16);
}

// ---------------- transpose + convert: dst[n][k] = bf16(src[k][n]), 1024x1024
__global__ __launch_bounds__(256) void transpose_cvt(const float* __restrict__ src,
                                                     unsigned short* __restrict__ dst) {
  __shared__ unsigned short tile[32][36];
  int b = blockIdx.x;
  int tr = b >> 5, tc = b & 31;
  int t = threadIdx.x;
  int i = t >> 3, j4 = (t & 7) << 2;
  const float4 v = *(const float4*)(src + (size_t)(tr * 32 + i) * 1024 + tc * 32 + j4);
  tile[i][j4 + 0] = f2bf(v.x);
  tile[i][j4 + 1] = f2bf(v.y);
  tile[i][j4 + 2] = f2bf(v.z);
  tile[i][j4 + 3] = f2bf(v.w);
  __syncthreads();
  int c = t >> 3, r4 = (t & 7) << 2;
  short4v o;
  o[0] = (short)tile[r4 + 0][c];
  o[1] = (short)tile[r4 + 1][c];
  o[2] = (short)tile[r4 + 2][c];
  o[3] = (short)tile[r4 + 3][c];
  *(short4v*)(dst + (size_t)(tc * 32 + c) * 1024 + tr * 32 + r4) = o;
}

// ---------------- xW GEMM: C[M,1024] = A[M,1024] @ B + bias, B given as B^T bf16 [N][K]
__global__ __launch_bounds__(256, 2) void xw_gemm(const float* __restrict__ A,
                                                  const unsigned short* __restrict__ BT,
                                                  const float* __restrict__ bias,
                                                  float* __restrict__ C) {
  __shared__ unsigned short As[128][40];
  __shared__ unsigned short Bs[128][40];
  int b = blockIdx.x;
  int swz = (b & 7) * 256 + (b >> 3);
  int tn = swz & 7, tm = swz >> 3;
  int t = threadIdx.x, lane = t & 63, wave = t >> 6;
  int l15 = lane & 15, l4 = lane >> 4;
  int wm = wave >> 1, wn = wave & 1;

  f32x4 acc[4][4];
#pragma unroll
  for (int i = 0; i < 4; ++i)
#pragma unroll
    for (int j = 0; j < 4; ++j) acc[i][j] = (f32x4){0.f, 0.f, 0.f, 0.f};

  int sm = t >> 1, sh = (t & 1) << 4;
  const float* a_src = A + (size_t)(tm * 128 + sm) * 1024 + sh;
  const unsigned short* b_src = BT + (size_t)(tn * 128 + sm) * 1024 + sh;

  for (int kt = 0; kt < 32; ++kt) {
    float4 av0 = *(const float4*)(a_src + kt * 32 + 0);
    float4 av1 = *(const float4*)(a_src + kt * 32 + 4);
    float4 av2 = *(const float4*)(a_src + kt * 32 + 8);
    float4 av3 = *(const float4*)(a_src + kt * 32 + 12);
    short8 w0, w1;
    w0[0] = (short)f2bf(av0.x); w0[1] = (short)f2bf(av0.y);
    w0[2] = (short)f2bf(av0.z); w0[3] = (short)f2bf(av0.w);
    w0[4] = (short)f2bf(av1.x); w0[5] = (short)f2bf(av1.y);
    w0[6] = (short)f2bf(av1.z); w0[7] = (short)f2bf(av1.w);
    w1[0] = (short)f2bf(av2.x); w1[1] = (short)f2bf(av2.y);
    w1[2] = (short)f2bf(av2.z); w1[3] = (short)f2bf(av2.w);
    w1[4] = (short)f2bf(av3.x); w1[5] = (short)f2bf(av3.y);
    w1[6] = (short)f2bf(av3.z); w1[7] = (short)f2bf(av3.w);
    *(short8*)&As[sm][sh] = w0;
    *(short8*)&As[sm][sh + 8] = w1;
    short8 bv0 = *(const short8*)(b_src + kt * 32 + 0);
    short8 bv1 = *(const short8*)(b_src + kt * 32 + 8);
    *(short8*)&Bs[sm][sh] = bv0;
    *(short8*)&Bs[sm][sh + 8] = bv1;
    __syncthreads();

    short8 af[4], bfr[4];
#pragma unroll
    for (int i = 0; i < 4; ++i) af[i] = *(const short8*)&As[wm * 64 + i * 16 + l15][8 * l4];
#pragma unroll
    for (int j = 0; j < 4; ++j) bfr[j] = *(const short8*)&Bs[wn * 64 + j * 16 + l15][8 * l4];
#pragma unroll
    for (int i = 0; i < 4; ++i)
#pragma unroll
      for (int j = 0; j < 4; ++j)
        acc[i][j] = __builtin_amdgcn_mfma_f32_16x16x32_bf16(af[i], bfr[j], acc[i][j], 0, 0, 0);
    __syncthreads();
  }

#pragma unroll
  for (int i = 0; i < 4; ++i) {
    int row0 = tm * 128 + wm * 64 + i * 16 + l4 * 4;
#pragma unroll
    for (int j = 0; j < 4; ++j) {
      int col = tn * 128 + wn * 64 + j * 16 + l15;
      float bv = bias[col];
#pragma unroll
      for (int r = 0; r < 4; ++r)
        C[(size_t)(row0 + r) * 1024 + col] = acc[i][j][r] + bv;
    }
  }
}

// ---------------- device-coherent (sc0 sc1) primitives — PROVEN transport path
__device__ __forceinline__ void coh_store_short(unsigned short* p, unsigned int v) {
  asm volatile("global_store_short %0, %1, off sc0 sc1" ::"v"(p), "v"(v) : "memory");
}
__device__ __forceinline__ void coh_store_dword(int* p, int v) {
  asm volatile("global_store_dword %0, %1, off sc0 sc1" ::"v"(p), "v"(v) : "memory");
}
__device__ __forceinline__ int coh_load_dword(const int* p) {
  int r;
  asm volatile("global_load_dword %0, %1, off sc0 sc1\n\ts_waitcnt vmcnt(0)"
               : "=v"(r) : "v"(p) : "memory");
  return r;
}
__device__ __forceinline__ void coh_load_x4(int4v* dst, const int* p) {
  asm volatile("global_load_dwordx4 %0, %1, off sc0 sc1" : "=&v"(*dst) : "v"(p) : "memory");
}

// =================================================================
// Protocol A (R2-proven): flags + ushort h, 256 WGs, LDS weights.
// Also dual-stores tagged dwords into hb2 for the handoff to B.
// =================================================================
__global__ __launch_bounds__(256, 1) void scan_flags(const unsigned short* __restrict__ whhT,
                                                     float* __restrict__ out,
                                                     unsigned short* __restrict__ hbu,
                                                     int* __restrict__ hb2,
                                                     int* __restrict__ flags,
                                                     int s0, int s1) {
  int wg = blockIdx.x;
  int xcd = wg & 7;
  int bg = xcd >> 1;
  int cg = ((wg >> 3) << 1) | (xcd & 1);
  int t = threadIdx.x, lane = t & 63, wave = t >> 6;
  int l15 = lane & 15, l4 = lane >> 4;

  __shared__ unsigned short wt[16][1032];
  __shared__ __align__(16) float red[4][64][4];

  {
    int row = t >> 4, seg = t & 15;
    const unsigned short* src = whhT + (size_t)(cg * 16 + row) * 1024 + seg * 64;
    unsigned short* dstp = &wt[row][seg * 64];
#pragma unroll
    for (int j = 0; j < 8; ++j) *(short8*)(dstp + j * 8) = *(const short8*)(src + j * 8);
  }
  __syncthreads();

  const int* fl = flags + bg * 64 + lane;

  for (int s = s0; s < s1; ++s) {
    f32x4 acc = (f32x4){0.f, 0.f, 0.f, 0.f};
    if (s > 0) {
      int guard = 0;
      for (;;) {
        int v = coh_load_dword(fl);
        if (__all(v >= s)) break;
        if (++guard > (1 << 20)) break;  // never hang
        __builtin_amdgcn_s_sleep(1);
      }
      const unsigned short* hprev = hbu + (size_t)((s - 1) & 1) * BATCH * HDIM;
      const unsigned short* arow = hprev + (size_t)(bg * 16 + l15) * HDIM + wave * 256 + 8 * l4;
      short8 a[8];
#pragma unroll
      for (int i = 0; i < 8; ++i)
        asm volatile("global_load_dwordx4 %0, %1, off sc0 sc1"
                     : "=&v"(a[i]) : "v"(arow + i * 32) : "memory");
      asm volatile("s_waitcnt vmcnt(0)" ::: "memory");
      __builtin_amdgcn_sched_barrier(0);
#pragma unroll
      for (int i = 0; i < 8; ++i) {
        short8 bfrag = *(const short8*)&wt[l15][wave * 256 + i * 32 + 8 * l4];
        acc = __builtin_amdgcn_mfma_f32_16x16x32_bf16(a[i], bfrag, acc, 0, 0, 0);
      }
    }
    *(f32x4*)&red[wave][lane][0] = acc;
    __syncthreads();
    float sum = red[0][lane][wave] + red[1][lane][wave] + red[2][lane][wave] + red[3][lane][wave];
    int row = bg * 16 + l4 * 4 + wave;
    int col = cg * 16 + l15;
    size_t oidx = ((size_t)s * BATCH + row) * HDIM + col;
    float hv = tanhf(out[oidx] + sum);
    out[oidx] = hv;
    unsigned short hb = f2bf(hv);
    size_t hoff = (size_t)(s & 1) * BATCH * HDIM + (size_t)row * HDIM + col;
    coh_store_short(hbu + hoff, (unsigned int)hb);
    coh_store_dword(hb2 + hoff, (int)(((unsigned)(s + 1) << 16) | (unsigned)hb));  // handoff
    if (s == T_STEPS - 1)
      out[(size_t)MROWS * HDIM + (size_t)row * HDIM + col] = hv;
    asm volatile("s_waitcnt vmcnt(0)" ::: "memory");
    __syncthreads();
    if (t == 0 && s != T_STEPS - 1)
      coh_store_dword(flags + bg * 64 + cg, s + 1);
  }
}

// =================================================================
// Protocols B/C/D (R4-proven base): 64 WGs, VGPR weights, tagged-dword h.
// NOSLEEP: tight spin (no s_sleep). CHUNKED: per-producer K-64 chunk
// verify+MFMA (absorbs producer jitter into compute).
// =================================================================
template <int NOSLEEP, int CHUNKED>
__global__ __launch_bounds__(256, 1) void scan_tag(const unsigned short* __restrict__ whhT,
                                                   float* __restrict__ out,
                                                   int* __restrict__ hb2,
                                                   int s0, int s1) {
  int wg = blockIdx.x;
  int bg = wg >> 4;   // 0..3
  int cg = wg & 15;   // 0..15
  int t = threadIdx.x, lane = t & 63, wave = t >> 6;
  int l15 = lane & 15, l4 = lane >> 4;

  __shared__ __align__(16) float red[2][4][64][4][4];

  short8 wfrag[4][8];
#pragma unroll
  for (int c = 0; c < 4; ++c)
#pragma unroll
    for (int m = 0; m < 8; ++m)
      wfrag[c][m] = *(const short8*)(whhT + (size_t)(64 * cg + 16 * c + l15) * 1024 +
                                     256 * wave + 32 * m + 8 * l4);

  int colw = 64 * cg + 16 * wave + l15;

  for (int s = s0; s < s1; ++s) {
    float xw[4];
#pragma unroll
    for (int r = 0; r < 4; ++r)
      xw[r] = out[((size_t)s * BATCH + bg * 16 + l4 * 4 + r) * HDIM + colw];

    f32x4 acc[4];
#pragma unroll
    for (int c = 0; c < 4; ++c) acc[c] = (f32x4){0.f, 0.f, 0.f, 0.f};

    if (s > 0) {
      const unsigned tagv = (unsigned)s;
      const int* base = hb2 + (((s - 1) & 1) << 16) + (16 * bg + l15) * 1024 + 256 * wave;

      if constexpr (CHUNKED) {
        // per-producer chunk: jj covers K [64jj,64jj+64) of this wave's slice
#pragma unroll
        for (int jj = 0; jj < 4; ++jj) {
          const int* fb = base + 64 * jj + 8 * l4;
          int4v c0, c1, c2, c3;
          int guard = 0;
          for (;;) {
            coh_load_x4(&c0, fb);
            coh_load_x4(&c1, fb + 4);
            coh_load_x4(&c2, fb + 32);
            coh_load_x4(&c3, fb + 36);
            asm volatile("s_waitcnt vmcnt(0)" ::: "memory");
            __builtin_amdgcn_sched_barrier(0);
            unsigned bad = 0;
#pragma unroll
            for (int e = 0; e < 4; ++e)
              bad |= (((unsigned)c0[e] >> 16) ^ tagv) | (((unsigned)c1[e] >> 16) ^ tagv) |
                     (((unsigned)c2[e] >> 16) ^ tagv) | (((unsigned)c3[e] >> 16) ^ tagv);
            if (__all(bad == 0)) break;
            if (++guard > 16384) break;
          }
          int4v p0, p1;
          p0[0] = (c0[0] & 0xffff) | (c0[1] << 16);
          p0[1] = (c0[2] & 0xffff) | (c0[3] << 16);
          p0[2] = (c1[0] & 0xffff) | (c1[1] << 16);
          p0[3] = (c1[2] & 0xffff) | (c1[3] << 16);
          p1[0] = (c2[0] & 0xffff) | (c2[1] << 16);
          p1[1] = (c2[2] & 0xffff) | (c2[3] << 16);
          p1[2] = (c3[0] & 0xffff) | (c3[1] << 16);
          p1[3] = (c3[2] & 0xffff) | (c3[3] << 16);
#pragma unroll
          for (int c = 0; c < 4; ++c) {
            acc[c] = __builtin_amdgcn_mfma_f32_16x16x32_bf16(*(short8*)&p0, wfrag[c][2 * jj],
                                                             acc[c], 0, 0, 0);
            acc[c] = __builtin_amdgcn_mfma_f32_16x16x32_bf16(*(short8*)&p1, wfrag[c][2 * jj + 1],
                                                             acc[c], 0, 0, 0);
          }
        }
      } else {
        const int* sp = base + 64 * l4 + 4 * l15;
        int4v q[16];
        int guard = 0;
        for (;;) {
          for (;;) {  // cheap sentinel probe (first probe immediate)
            int4v sv;
            coh_load_x4(&sv, sp);
            asm volatile("s_waitcnt vmcnt(0)" ::: "memory");
            unsigned bad = (((unsigned)sv[0] >> 16) ^ tagv) | (((unsigned)sv[1] >> 16) ^ tagv) |
                           (((unsigned)sv[2] >> 16) ^ tagv) | (((unsigned)sv[3] >> 16) ^ tagv);
            if (__all(bad == 0)) break;
            if (++guard > 16384) break;
            if constexpr (!NOSLEEP) __builtin_amdgcn_s_sleep(2);
          }
#pragma unroll
          for (int jj = 0; jj < 4; ++jj) {
            const int* fb = base + 64 * jj + 8 * l4;
            coh_load_x4(&q[jj * 4 + 0], fb);
            coh_load_x4(&q[jj * 4 + 1], fb + 4);
            coh_load_x4(&q[jj * 4 + 2], fb + 32);
            coh_load_x4(&q[jj * 4 + 3], fb + 36);
          }
          asm volatile("s_waitcnt vmcnt(0)" ::: "memory");
          __builtin_amdgcn_sched_barrier(0);
          unsigned bad = 0;
#pragma unroll
          for (int i = 0; i < 16; ++i)
            bad |= (((unsigned)q[i][0] >> 16) ^ tagv) | (((unsigned)q[i][1] >> 16) ^ tagv) |
                   (((unsigned)q[i][2] >> 16) ^ tagv) | (((unsigned)q[i][3] >> 16) ^ tagv);
          if (__all(bad == 0)) break;
          if (guard > 16384) break;
          if constexpr (!NOSLEEP) __builtin_amdgcn_s_sleep(1);
        }
#pragma unroll
        for (int jj = 0; jj < 4; ++jj) {
          int4v a0 = q[jj * 4 + 0], a1 = q[jj * 4 + 1], a2 = q[jj * 4 + 2], a3 = q[jj * 4 + 3];
          int4v p0, p1;
          p0[0] = (a0[0] & 0xffff) | (a0[1] << 16);
          p0[1] = (a0[2] & 0xffff) | (a0[3] << 16);
          p0[2] = (a1[0] & 0xffff) | (a1[1] << 16);
          p0[3] = (a1[2] & 0xffff) | (a1[3] << 16);
          p1[0] = (a2[0] & 0xffff) | (a2[1] << 16);
          p1[1] = (a2[2] & 0xffff) | (a2[3] << 16);
          p1[2] = (a3[0] & 0xffff) | (a3[1] << 16);
          p1[3] = (a3[2] & 0xffff) | (a3[3] << 16);
#pragma unroll
          for (int c = 0; c < 4; ++c) {
            acc[c] = __builtin_amdgcn_mfma_f32_16x16x32_bf16(*(short8*)&p0, wfrag[c][2 * jj],
                                                             acc[c], 0, 0, 0);
            acc[c] = __builtin_amdgcn_mfma_f32_16x16x32_bf16(*(short8*)&p1, wfrag[c][2 * jj + 1],
                                                             acc[c], 0, 0, 0);
          }
        }
      }
    }

    int p = s & 1;
#pragma unroll
    for (int c = 0; c < 4; ++c) *(f32x4*)&red[p][wave][lane][c][0] = acc[c];
    __syncthreads();
    f32x4 hsum;
#pragma unroll
    for (int r = 0; r < 4; ++r)
      hsum[r] = red[p][0][lane][wave][r] + red[p][1][lane][wave][r] +
                red[p][2][lane][wave][r] + red[p][3][lane][wave][r];

#pragma unroll
    for (int r = 0; r < 4; ++r) {
      int row = bg * 16 + l4 * 4 + r;
      size_t oidx = ((size_t)s * BATCH + row) * HDIM + colw;
      float hv = tanhf(xw[r] + hsum[r]);
      out[oidx] = hv;
      if (s != T_STEPS - 1)
        coh_store_dword(hb2 + ((s & 1) << 16) + row * 1024 + colw,
                        (int)(((unsigned)(s + 1) << 16) | (unsigned)f2bf(hv)));
      else
        out[(size_t)MROWS * HDIM + (size_t)row * HDIM + colw] = hv;
    }
  }
}

extern "C" void kernel_launch(void* const* d_in, const int* in_sizes, int n_in,
                              void* d_out, int out_size, void* d_ws, size_t ws_size,
                              hipStream_t stream) {
  const float* inp = (const float*)d_in[0];   // [512,64,1024] fp32
  const float* wxh = (const float*)d_in[1];   // [1024,1024]
  const float* whh = (const float*)d_in[2];   // [1024,1024]
  const float* bh  = (const float*)d_in[3];   // [1024]
  float* out = (float*)d_out;

  char* ws = (char*)d_ws;
  unsigned short* whhT = (unsigned short*)(ws);                       // 2 MB
  unsigned short* wxhT = (unsigned short*)(ws + (2u << 20));          // 2 MB
  unsigned short* hbu = (unsigned short*)(ws + (4u << 20));           // 256 KB ushort h
  int* hb2 = (int*)(ws + (4u << 20) + (256u << 10));                  // 512 KB tagged h
  int* flags = (int*)(ws + (4u << 20) + (768u << 10));                // 4 KB

  hipMemsetAsync(ws + (4u << 20), 0, (772u << 10), stream);  // hbu + hb2 + flags
  transpose_cvt<<<1024, 256, 0, stream>>>(whh, whhT);
  transpose_cvt<<<1024, 256, 0, stream>>>(wxh, wxhT);
  xw_gemm<<<2048, 256, 0, stream>>>(inp, wxhT, bh, out);
  // A: proven flags protocol (steps 0-127), dual-stores tagged h for handoff
  scan_flags<<<256, 256, 0, stream>>>(whhT, out, hbu, hb2, flags, 0, 128);
  // B: proven sentinel+bulk tagged protocol (128-255)
  scan_tag<0, 0><<<64, 256, 0, stream>>>(whhT, out, hb2, 128, 256);
  // C: B without sleeps (256-383)
  scan_tag<1, 0><<<64, 256, 0, stream>>>(whhT, out, hb2, 256, 384);
  // D: per-producer chunked consume (384-511)
  scan_tag<1, 1><<<64, 256, 0, stream>>>(whhT, out, hb2, 384, 512);
}